// Round 14
// baseline (257.354 us; speedup 1.0000x reference)
//
#include <hip/hip_runtime.h>
#include <hip/hip_bf16.h>

typedef __bf16 bf16_t;
typedef bf16_t bf16x8 __attribute__((ext_vector_type(8)));
typedef bf16_t bf16x4 __attribute__((ext_vector_type(4)));
typedef float  f32x4  __attribute__((ext_vector_type(4)));

constexpr int S = 2048, D = 256;

// ---------------- ws layout (bytes) ----------------
// wtf   : [2][16 nt][8 ks][64 lane][8] bf16 (frag W^T q,k)  @ 0        (262144)
// xf    : frag layout [2048 qb][8 ks][64 lane][8] bf16      @ 262144   (16777216)
// q     : frag layout [B][128 qb][8 ks][64 lane][8] bf16    @ 17039360 (16777216)
// k     : frag layout [B][128 kb][8 ks][64 lane][8] bf16    @ 33816576 (16777216)
// lpart : [16 kh][16 b][2048] f32                           @ 50593792 (2097152)
// wpart : [8 qt][16 b][2048] f32                            @ 52690944 (1048576)
// gpart : [16 kseg][16 b][256] f32                          @ 53739520 (262144)
// total : ~54 MB.  V is NEVER materialized:
//   out = (sum_k w_k x_k) @ Wv + 2048*bv   (sum_k w_k == #queries exactly)

__device__ __forceinline__ float fast_exp2(float x) {
    return __builtin_amdgcn_exp2f(x);
}

// Kernel 1: Wq/Wk -> bf16 fragment-major.
__global__ void wt_kernel(const float* __restrict__ Wq, const float* __restrict__ Wk,
                          bf16_t* __restrict__ wtf) {
    int idx = blockIdx.x * 256 + threadIdx.x;   // [0, 16384)
    int w    = idx >> 13;
    int rem  = idx & 8191;
    int nt   = rem >> 9;
    int rem2 = rem & 511;
    int ks   = rem2 >> 6;
    int lane = rem2 & 63;
    int lm = lane & 15, lg = lane >> 4;
    const float* Wsrc = (w == 0) ? Wq : Wk;
    int col = nt * 16 + lm, krow = ks * 32 + lg * 8;
    bf16x8 o;
#pragma unroll
    for (int j = 0; j < 8; j++) o[j] = (bf16_t)Wsrc[(krow + j) * 256 + col];
    *(bf16x8*)(wtf + (size_t)idx * 8) = o;
}

// Kernel 1b: x (fp32 row-major) -> xf (bf16 fragment-major). grid 512 x 256.
__global__ __launch_bounds__(256) void xconv_kernel(
    const float* __restrict__ x, bf16_t* __restrict__ xf) {
    __shared__ bf16_t xt[4][4096];           // 8 KB per wave
    int tid = threadIdx.x, wave = tid >> 6, lane = tid & 63;
    int qb = blockIdx.x * 4 + wave;          // [0, 2048)
    const float* xr = x + (size_t)qb * 16 * 256;
    bf16_t* buf = xt[wave];
    int ks = lane >> 3, lg = (lane & 7) >> 1, j = (lane & 1) * 4;
#pragma unroll
    for (int rr = 0; rr < 16; rr++) {
        float4 f = *(const float4*)(xr + rr * 256 + lane * 4);
        bf16x4 o;
        o[0] = (bf16_t)f.x; o[1] = (bf16_t)f.y; o[2] = (bf16_t)f.z; o[3] = (bf16_t)f.w;
        *(bf16x4*)&buf[(ks * 64 + lg * 16 + rr) * 8 + j] = o;
    }
    bf16_t* dst = xf + (size_t)qb * 4096;
#pragma unroll
    for (int k2 = 0; k2 < 8; k2++) {
        bf16x8 v = *(const bf16x8*)&buf[k2 * 512 + lane * 8];
        *(bf16x8*)(dst + k2 * 512 + lane * 8) = v;
    }
}

// Kernel 2: Q/K projection, GEMM-tiled. grid (512 = 256 rowb x 2 colh, 2 w),
// 256 thr (4 waves as 2 rowg x 2 colg). B-frags (64 KB) staged to LDS once;
// A-frags contiguous lane*16B bursts from xf.
__global__ __launch_bounds__(256, 2) void proj_kernel(
    const bf16_t* __restrict__ xf, const bf16_t* __restrict__ wtf,
    const float* __restrict__ bq, const float* __restrict__ bk,
    bf16_t* __restrict__ qo, bf16_t* __restrict__ ko) {
    __shared__ bf16_t bst[32768];          // 8 nt x 8 ks x 512  (64 KB)
    __shared__ bf16_t sb_all[4][1152];     // epilogue transpose: 16 x 72 per wave
    int w    = blockIdx.y;
    int tid  = threadIdx.x;
    int wave = tid >> 6, lane = tid & 63, lm = lane & 15, lg = lane >> 4;
    int rowb = blockIdx.x >> 1;
    int colh = blockIdx.x & 1;
    int rowg = wave >> 1, colg = wave & 1;
    const float* bias = (w == 0) ? bq : bk;

    {
        const bf16_t* src = wtf + w * 65536 + (size_t)colh * 32768;
#pragma unroll
        for (int rnd = 0; rnd < 4; rnd++) {
            bf16x8 tmp[4];
#pragma unroll
            for (int u = 0; u < 4; u++)
                tmp[u] = *(const bf16x8*)(src + (size_t)((rnd * 4 + u) * 256 + tid) * 8);
#pragma unroll
            for (int u = 0; u < 4; u++)
                *(bf16x8*)&bst[(size_t)((rnd * 4 + u) * 256 + tid) * 8] = tmp[u];
        }
    }

    int qb0 = rowb * 8 + rowg * 4;
    bf16x8 af[4][8];
#pragma unroll
    for (int s = 0; s < 4; s++) {
        const bf16_t* ab = xf + (size_t)(qb0 + s) * 4096;
#pragma unroll
        for (int ks = 0; ks < 8; ks++)
            af[s][ks] = *(const bf16x8*)(ab + ks * 512 + lane * 8);
    }
    __syncthreads();

    f32x4 acc[4][4];
#pragma unroll
    for (int s = 0; s < 4; s++)
#pragma unroll
        for (int nt = 0; nt < 4; nt++) acc[s][nt] = f32x4{0.f, 0.f, 0.f, 0.f};
#pragma unroll
    for (int ks = 0; ks < 8; ks++) {
#pragma unroll
        for (int nt = 0; nt < 4; nt++) {
            bf16x8 bfr = *(const bf16x8*)&bst[(size_t)(((colg * 4 + nt) * 8 + ks) * 512) + lane * 8];
#pragma unroll
            for (int s = 0; s < 4; s++)
                acc[s][nt] = __builtin_amdgcn_mfma_f32_16x16x32_bf16(af[s][ks], bfr, acc[s][nt], 0, 0, 0);
        }
    }

    bf16_t* sb = sb_all[wave];
    bf16_t* dst = (w == 0) ? qo : ko;
    int c0 = colh * 128 + colg * 64;
#pragma unroll
    for (int s = 0; s < 4; s++) {
#pragma unroll
        for (int nt = 0; nt < 4; nt++) {
            int colloc = nt * 16 + lm;
            float bval = bias[c0 + colloc];
#pragma unroll
            for (int r = 0; r < 4; r++)
                sb[(lg * 4 + r) * 72 + colloc] = (bf16_t)(acc[s][nt][r] + bval);
        }
#pragma unroll
        for (int kk = 0; kk < 2; kk++) {
            bf16x8 v8 = *(const bf16x8*)&sb[lm * 72 + kk * 32 + lg * 8];
            *(bf16x8*)(dst + ((size_t)((qb0 + s) * 8 + (c0 >> 5) + kk)) * 512 + lane * 8) = v8;
        }
    }
}

// Kernels 3/4: QK^T passes, STAGE-ONCE / BARRIER-ONCE.
// grid 2048 = (16 b x 8 qt(256 rows) x 16 kh(128 keys)), 256 thr (4 waves).
// The block's 128-key K chunk (64 KB) is staged to LDS ONCE; after a single
// __syncthreads the compute phase (64 ds_reads + 256 MFMAs per wave) is
// completely barrier-free (R13 lesson: per-tile barriers at 2 waves/SIMD are
// unabsorbable; R11 lesson: skipping LDS costs 8x L2 + latency).
// Wave owns 64 q-rows (4 A-sets resident, no launch-bounds VGPR cap).
// PASS=1: l -> lpart.  PASS=2: w -> wpart (rinv folded into exponent).
template <int PASS>
__global__ __launch_bounds__(256) void attn_pass(
    const bf16_t* __restrict__ q, const bf16_t* __restrict__ kmat,
    float* __restrict__ lpart, float* __restrict__ wpart) {
    __shared__ bf16_t kst[32768];             // 64 KB: [8 kb][8 ks][512]
    __shared__ float  wacc[4][128];           // PASS 2 only (2 KB)

    int tid  = threadIdx.x;
    int wave = tid >> 6, lane = tid & 63, lm = lane & 15, lg = lane >> 4;
    int i    = blockIdx.x;                    // 2048 blocks
    int b    = (i & 7) * 2 + ((i >> 10) & 1); // XCD-aware: 2 batches per XCD
    int qt   = (i >> 3) & 7;                  // 8 q-tiles of 256 rows
    int kh   = (i >> 6) & 15;                 // 16 key chunks of 128

    // ---- stage K chunk (64 KB) to LDS: 16 x bf16x8 per thread ----
    {
        const bf16_t* src = kmat + (size_t)(b * 128 + kh * 8) * 4096;
        bf16x8 stg[16];
#pragma unroll
        for (int u = 0; u < 16; u++)
            stg[u] = *(const bf16x8*)(src + (size_t)(u * 256 + tid) * 8);
#pragma unroll
        for (int u = 0; u < 16; u++)
            *(bf16x8*)&kst[(u * 256 + tid) * 8] = stg[u];
    }

    // ---- A-frags: 4 sets x 16 q-rows = 64 q-rows per wave ----
    bf16x8 af[4][8];
#pragma unroll
    for (int s = 0; s < 4; s++) {
        const bf16_t* qb = q + ((size_t)((b * 128 + qt * 16 + wave * 4 + s) * 8)) * 512;
#pragma unroll
        for (int ks = 0; ks < 8; ks++)
            af[s][ks] = *(const bf16x8*)(qb + ks * 512 + lane * 8);
    }

    constexpr float SCL = 0.0625f * 1.44269504f;

    float lr[4][4];                           // PASS2: -log2(l) per row
    if (PASS == 2) {
#pragma unroll
        for (int s = 0; s < 4; s++)
#pragma unroll
            for (int r = 0; r < 4; r++) {
                int row = qt * 256 + wave * 64 + s * 16 + lg * 4 + r;
                float l = 0.f;
#pragma unroll
                for (int k2 = 0; k2 < 16; k2++)
                    l += lpart[(size_t)(k2 * 16 + b) * 2048 + row];
                lr[s][r] = -__builtin_log2f(l);
            }
    }

    float lsum[4][4];
#pragma unroll
    for (int s = 0; s < 4; s++)
#pragma unroll
        for (int r = 0; r < 4; r++) lsum[s][r] = 0.f;

    __syncthreads();   // the ONLY barrier before the epilogue

    // ---- compute: barrier-free sweep over 4 pairs of 16-key blocks ----
#pragma unroll
    for (int kp = 0; kp < 4; kp++) {
        f32x4 sacc[4][2];
#pragma unroll
        for (int s = 0; s < 4; s++) {
            sacc[s][0] = f32x4{0.f, 0.f, 0.f, 0.f};
            sacc[s][1] = f32x4{0.f, 0.f, 0.f, 0.f};
        }
#pragma unroll
        for (int ks = 0; ks < 8; ks++) {
            bf16x8 b0 = *(const bf16x8*)&kst[((kp * 2 + 0) * 8 + ks) * 512 + lane * 8];
            bf16x8 b1 = *(const bf16x8*)&kst[((kp * 2 + 1) * 8 + ks) * 512 + lane * 8];
#pragma unroll
            for (int s = 0; s < 4; s++) {
                sacc[s][0] = __builtin_amdgcn_mfma_f32_16x16x32_bf16(af[s][ks], b0, sacc[s][0], 0, 0, 0);
                sacc[s][1] = __builtin_amdgcn_mfma_f32_16x16x32_bf16(af[s][ks], b1, sacc[s][1], 0, 0, 0);
            }
        }
        if (PASS == 1) {
#pragma unroll
            for (int s = 0; s < 4; s++)
#pragma unroll
                for (int j = 0; j < 2; j++)
#pragma unroll
                    for (int r = 0; r < 4; r++)
                        lsum[s][r] += fast_exp2(sacc[s][j][r] * SCL);
        } else {
#pragma unroll
            for (int j = 0; j < 2; j++) {
                float wv = 0.f;
#pragma unroll
                for (int s = 0; s < 4; s++)
#pragma unroll
                    for (int r = 0; r < 4; r++)
                        wv += fast_exp2(__builtin_fmaf(sacc[s][j][r], SCL, lr[s][r]));
                wv += __shfl_xor(wv, 16);
                wv += __shfl_xor(wv, 32);
                if (lg == 0) wacc[wave][kp * 32 + j * 16 + lm] = wv;
            }
        }
    }

    if (PASS == 1) {
#pragma unroll
        for (int s = 0; s < 4; s++)
#pragma unroll
            for (int r = 0; r < 4; r++) {
                float v2 = lsum[s][r];
                v2 += __shfl_xor(v2, 1);
                v2 += __shfl_xor(v2, 2);
                v2 += __shfl_xor(v2, 4);
                v2 += __shfl_xor(v2, 8);
                if (lm == 0) {
                    int row = qt * 256 + wave * 64 + s * 16 + lg * 4 + r;
                    lpart[(size_t)(kh * 16 + b) * 2048 + row] = v2;
                }
            }
    } else {
        __syncthreads();
        if (tid < 128) {
            float sum = wacc[0][tid] + wacc[1][tid] + wacc[2][tid] + wacc[3][tid];
            wpart[(size_t)(qt * 16 + b) * 2048 + kh * 128 + tid] = sum;
        }
    }
}

// Kernel 5: gpart[kseg,b,d] = sum over 128 keys of w_k x[b,k,d] (fp32 x).
__global__ __launch_bounds__(256) void xsum_kernel(
    const float* __restrict__ wpart, const float* __restrict__ x,
    float* __restrict__ gpart) {
    __shared__ float ldsw[128];
    int b = blockIdx.x >> 4, kseg = blockIdx.x & 15, tid = threadIdx.x;
    if (tid < 128) {
        int key = kseg * 128 + tid;
        float s = 0.f;
#pragma unroll
        for (int qt = 0; qt < 8; qt++) s += wpart[(size_t)(qt * 16 + b) * 2048 + key];
        ldsw[tid] = s;
    }
    __syncthreads();
    const float* xb = x + ((size_t)b * 2048 + kseg * 128) * 256;
    float acc = 0.f;
#pragma unroll 8
    for (int t = 0; t < 128; t++) acc += ldsw[t] * xb[(size_t)t * 256 + tid];
    gpart[(size_t)(kseg * 16 + b) * 256 + tid] = acc;
}

// Kernel 6: out[b,d] = (sum_kseg gpart)[b,:] @ Wv[:,d] + 2048*bv[d].
__global__ __launch_bounds__(256) void final_kernel(
    const float* __restrict__ gpart, const float* __restrict__ Wv,
    const float* __restrict__ bv, float* __restrict__ out) {
    __shared__ float yl[256];
    int b = blockIdx.x, tid = threadIdx.x;
    float s = 0.f;
#pragma unroll
    for (int ks = 0; ks < 16; ks++) s += gpart[(size_t)(ks * 16 + b) * 256 + tid];
    yl[tid] = s;
    __syncthreads();
    float acc = 0.f;
#pragma unroll 4
    for (int c = 0; c < 256; c++) acc += yl[c] * Wv[c * 256 + tid];
    out[b * 256 + tid] = acc + 2048.0f * bv[tid];
}

extern "C" void kernel_launch(void* const* d_in, const int* in_sizes, int n_in,
                              void* d_out, int out_size, void* d_ws, size_t ws_size,
                              hipStream_t stream) {
    const float* x  = (const float*)d_in[0];
    const float* Wq = (const float*)d_in[1];
    const float* bq = (const float*)d_in[2];
    const float* Wk = (const float*)d_in[3];
    const float* bk = (const float*)d_in[4];
    const float* Wv = (const float*)d_in[5];
    const float* bv = (const float*)d_in[6];
    float* out = (float*)d_out;

    char* ws = (char*)d_ws;
    bf16_t* wtf   = (bf16_t*)(ws);
    bf16_t* xf    = (bf16_t*)(ws + 262144);
    bf16_t* q     = (bf16_t*)(ws + 17039360);
    bf16_t* kmat  = (bf16_t*)(ws + 33816576);
    float*  lpart = (float*) (ws + 50593792);
    float*  wpart = (float*) (ws + 52690944);
    float*  gpart = (float*) (ws + 53739520);

    wt_kernel<<<dim3(64), dim3(256), 0, stream>>>(Wq, Wk, wtf);
    xconv_kernel<<<dim3(512), dim3(256), 0, stream>>>(x, xf);
    proj_kernel<<<dim3(512, 2), dim3(256), 0, stream>>>(xf, wtf, bq, bk, q, kmat);
    attn_pass<1><<<dim3(2048), dim3(256), 0, stream>>>(q, kmat, lpart, wpart);
    attn_pass<2><<<dim3(2048), dim3(256), 0, stream>>>(q, kmat, lpart, wpart);
    xsum_kernel<<<dim3(256), dim3(256), 0, stream>>>(wpart, x, gpart);
    final_kernel<<<dim3(16), dim3(256), 0, stream>>>(gpart, Wv, bv, out);
}

// Round 15
// 194.238 us; speedup vs baseline: 1.3249x; 1.3249x over previous
//
#include <hip/hip_runtime.h>
#include <hip/hip_bf16.h>

typedef __bf16 bf16_t;
typedef bf16_t bf16x8 __attribute__((ext_vector_type(8)));
typedef bf16_t bf16x4 __attribute__((ext_vector_type(4)));
typedef float  f32x4  __attribute__((ext_vector_type(4)));

constexpr int S = 2048, D = 256;

// ---------------- ws layout (bytes) ----------------
// wtf   : [2][16 nt][8 ks][64 lane][8] bf16 (frag W^T q,k)  @ 0        (262144)
// xf    : frag layout [2048 qb][8 ks][64 lane][8] bf16      @ 262144   (16777216)
// q     : frag layout [B][128 qb][8 ks][64 lane][8] bf16    @ 17039360 (16777216)
// k     : frag layout [B][128 kb][8 ks][64 lane][8] bf16    @ 33816576 (16777216)
// wpart : [32 qt][16 b][2048] f32                           @ 50593792 (4194304)
// gpart : [16 kseg][16 b][256] f32                          @ 54788096 (262144)
// total : ~55 MB.  V is NEVER materialized:
//   out = (sum_k w_k x_k) @ Wv + 2048*bv   (sum_k w_k == #queries exactly)
// lpart is GONE: attn is one fused kernel (block owns 64 rows x ALL keys).

__device__ __forceinline__ float fast_exp2(float x) {
    return __builtin_amdgcn_exp2f(x);
}

// Kernel 1: Wq/Wk -> bf16 fragment-major.
__global__ void wt_kernel(const float* __restrict__ Wq, const float* __restrict__ Wk,
                          bf16_t* __restrict__ wtf) {
    int idx = blockIdx.x * 256 + threadIdx.x;   // [0, 16384)
    int w    = idx >> 13;
    int rem  = idx & 8191;
    int nt   = rem >> 9;
    int rem2 = rem & 511;
    int ks   = rem2 >> 6;
    int lane = rem2 & 63;
    int lm = lane & 15, lg = lane >> 4;
    const float* Wsrc = (w == 0) ? Wq : Wk;
    int col = nt * 16 + lm, krow = ks * 32 + lg * 8;
    bf16x8 o;
#pragma unroll
    for (int j = 0; j < 8; j++) o[j] = (bf16_t)Wsrc[(krow + j) * 256 + col];
    *(bf16x8*)(wtf + (size_t)idx * 8) = o;
}

// Kernel 1b: x (fp32 row-major) -> xf (bf16 fragment-major). grid 512 x 256.
__global__ __launch_bounds__(256) void xconv_kernel(
    const float* __restrict__ x, bf16_t* __restrict__ xf) {
    __shared__ bf16_t xt[4][4096];           // 8 KB per wave
    int tid = threadIdx.x, wave = tid >> 6, lane = tid & 63;
    int qb = blockIdx.x * 4 + wave;          // [0, 2048)
    const float* xr = x + (size_t)qb * 16 * 256;
    bf16_t* buf = xt[wave];
    int ks = lane >> 3, lg = (lane & 7) >> 1, j = (lane & 1) * 4;
#pragma unroll
    for (int rr = 0; rr < 16; rr++) {
        float4 f = *(const float4*)(xr + rr * 256 + lane * 4);
        bf16x4 o;
        o[0] = (bf16_t)f.x; o[1] = (bf16_t)f.y; o[2] = (bf16_t)f.z; o[3] = (bf16_t)f.w;
        *(bf16x4*)&buf[(ks * 64 + lg * 16 + rr) * 8 + j] = o;
    }
    bf16_t* dst = xf + (size_t)qb * 4096;
#pragma unroll
    for (int k2 = 0; k2 < 8; k2++) {
        bf16x8 v = *(const bf16x8*)&buf[k2 * 512 + lane * 8];
        *(bf16x8*)(dst + k2 * 512 + lane * 8) = v;
    }
}

// Kernel 2: Q/K projection, GEMM-tiled (unchanged from R10-best).
__global__ __launch_bounds__(256, 2) void proj_kernel(
    const bf16_t* __restrict__ xf, const bf16_t* __restrict__ wtf,
    const float* __restrict__ bq, const float* __restrict__ bk,
    bf16_t* __restrict__ qo, bf16_t* __restrict__ ko) {
    __shared__ bf16_t bst[32768];          // 64 KB
    __shared__ bf16_t sb_all[4][1152];
    int w    = blockIdx.y;
    int tid  = threadIdx.x;
    int wave = tid >> 6, lane = tid & 63, lm = lane & 15, lg = lane >> 4;
    int rowb = blockIdx.x >> 1;
    int colh = blockIdx.x & 1;
    int rowg = wave >> 1, colg = wave & 1;
    const float* bias = (w == 0) ? bq : bk;

    {
        const bf16_t* src = wtf + w * 65536 + (size_t)colh * 32768;
#pragma unroll
        for (int rnd = 0; rnd < 4; rnd++) {
            bf16x8 tmp[4];
#pragma unroll
            for (int u = 0; u < 4; u++)
                tmp[u] = *(const bf16x8*)(src + (size_t)((rnd * 4 + u) * 256 + tid) * 8);
#pragma unroll
            for (int u = 0; u < 4; u++)
                *(bf16x8*)&bst[(size_t)((rnd * 4 + u) * 256 + tid) * 8] = tmp[u];
        }
    }

    int qb0 = rowb * 8 + rowg * 4;
    bf16x8 af[4][8];
#pragma unroll
    for (int s = 0; s < 4; s++) {
        const bf16_t* ab = xf + (size_t)(qb0 + s) * 4096;
#pragma unroll
        for (int ks = 0; ks < 8; ks++)
            af[s][ks] = *(const bf16x8*)(ab + ks * 512 + lane * 8);
    }
    __syncthreads();

    f32x4 acc[4][4];
#pragma unroll
    for (int s = 0; s < 4; s++)
#pragma unroll
        for (int nt = 0; nt < 4; nt++) acc[s][nt] = f32x4{0.f, 0.f, 0.f, 0.f};
#pragma unroll
    for (int ks = 0; ks < 8; ks++) {
#pragma unroll
        for (int nt = 0; nt < 4; nt++) {
            bf16x8 bfr = *(const bf16x8*)&bst[(size_t)(((colg * 4 + nt) * 8 + ks) * 512) + lane * 8];
#pragma unroll
            for (int s = 0; s < 4; s++)
                acc[s][nt] = __builtin_amdgcn_mfma_f32_16x16x32_bf16(af[s][ks], bfr, acc[s][nt], 0, 0, 0);
        }
    }

    bf16_t* sb = sb_all[wave];
    bf16_t* dst = (w == 0) ? qo : ko;
    int c0 = colh * 128 + colg * 64;
#pragma unroll
    for (int s = 0; s < 4; s++) {
#pragma unroll
        for (int nt = 0; nt < 4; nt++) {
            int colloc = nt * 16 + lm;
            float bval = bias[c0 + colloc];
#pragma unroll
            for (int r = 0; r < 4; r++)
                sb[(lg * 4 + r) * 72 + colloc] = (bf16_t)(acc[s][nt][r] + bval);
        }
#pragma unroll
        for (int kk = 0; kk < 2; kk++) {
            bf16x8 v8 = *(const bf16x8*)&sb[lm * 72 + kk * 32 + lg * 8];
            *(bf16x8*)(dst + ((size_t)((qb0 + s) * 8 + (c0 >> 5) + kk)) * 512 + lane * 8) = v8;
        }
    }
}

// Kernel 3: FUSED attention. grid 512 = (16 b x 32 qt of 64 rows), 256 thr.
// Block owns 64 q-rows x ALL 2048 keys; each wave privately owns a 512-key
// chunk (no duplication - R11 lesson) loaded global->REGISTER with manual
// double-buffer (no LDS pipe, no staging bursts - R14 lesson), af[4][8]
// resident via free VGPR allocation (R13 lesson), ZERO barriers in sweeps
// (R13 lesson). Sweep 1 computes l (complete in-block); one barrier + 1KB
// LDS reduce; sweep 2 recomputes scores (keys L2-hot) -> w_k direct to wpart.
__global__ __launch_bounds__(256) void attn_fused(
    const bf16_t* __restrict__ q, const bf16_t* __restrict__ kmat,
    float* __restrict__ wpart) {
    __shared__ float lbuf[4][64];

    int tid  = threadIdx.x;
    int wave = tid >> 6, lane = tid & 63, lm = lane & 15, lg = lane >> 4;
    int i    = blockIdx.x;                    // 512 blocks
    int b    = (i & 7) * 2 + ((i >> 8) & 1);  // XCD-aware: 2 batches per XCD
    int qt   = (i >> 3) & 31;                 // 32 q-tiles of 64 rows

    // A-frags: 4 sets x 16 q-rows = the block's 64 rows (same for all waves).
    bf16x8 af[4][8];
#pragma unroll
    for (int s = 0; s < 4; s++) {
        const bf16_t* qb = q + ((size_t)((b * 128 + qt * 4 + s) * 8)) * 512;
#pragma unroll
        for (int ks = 0; ks < 8; ks++)
            af[s][ks] = *(const bf16x8*)(qb + ks * 512 + lane * 8);
    }

    constexpr float SCL = 0.0625f * 1.44269504f;
    const bf16_t* kb = kmat + ((size_t)((b * 128 + wave * 32) * 8)) * 512;

    // ---- sweep 1: l over this wave's 512 keys (32 blocks of 16) ----
    float lsum[4][4];
#pragma unroll
    for (int s = 0; s < 4; s++)
#pragma unroll
        for (int r = 0; r < 4; r++) lsum[s][r] = 0.f;

    {
        bf16x8 cur[8], nxt[8];
#pragma unroll
        for (int u = 0; u < 8; u++)
            cur[u] = *(const bf16x8*)(kb + u * 512 + lane * 8);
        for (int t = 0; t < 32; t++) {
            if (t < 31) {
#pragma unroll
                for (int u = 0; u < 8; u++)
                    nxt[u] = *(const bf16x8*)(kb + (size_t)(t + 1) * 4096 + u * 512 + lane * 8);
            }
            f32x4 sacc[4];
#pragma unroll
            for (int s = 0; s < 4; s++) sacc[s] = f32x4{0.f, 0.f, 0.f, 0.f};
#pragma unroll
            for (int ks = 0; ks < 8; ks++)
#pragma unroll
                for (int s = 0; s < 4; s++)
                    sacc[s] = __builtin_amdgcn_mfma_f32_16x16x32_bf16(af[s][ks], cur[ks], sacc[s], 0, 0, 0);
#pragma unroll
            for (int s = 0; s < 4; s++)
#pragma unroll
                for (int r = 0; r < 4; r++)
                    lsum[s][r] += fast_exp2(sacc[s][r] * SCL);
            if (t < 31) {
#pragma unroll
                for (int u = 0; u < 8; u++) cur[u] = nxt[u];
            }
        }
    }

    // ---- block-wide l reduction (the only barrier) ----
#pragma unroll
    for (int s = 0; s < 4; s++)
#pragma unroll
        for (int r = 0; r < 4; r++) {
            float v2 = lsum[s][r];
            v2 += __shfl_xor(v2, 1);
            v2 += __shfl_xor(v2, 2);
            v2 += __shfl_xor(v2, 4);
            v2 += __shfl_xor(v2, 8);
            if (lm == 0) lbuf[wave][s * 16 + lg * 4 + r] = v2;
        }
    __syncthreads();
    float lr[4][4];
#pragma unroll
    for (int s = 0; s < 4; s++)
#pragma unroll
        for (int r = 0; r < 4; r++) {
            int row = s * 16 + lg * 4 + r;
            float l = lbuf[0][row] + lbuf[1][row] + lbuf[2][row] + lbuf[3][row];
            lr[s][r] = -__builtin_log2f(l);
        }

    // ---- sweep 2: w_k = sum_rows exp2(s*SCL - log2 l), keys L2-hot ----
    {
        float* wp = wpart + (size_t)(qt * 16 + b) * 2048 + wave * 512;
        bf16x8 cur[8], nxt[8];
#pragma unroll
        for (int u = 0; u < 8; u++)
            cur[u] = *(const bf16x8*)(kb + u * 512 + lane * 8);
        for (int t = 0; t < 32; t++) {
            if (t < 31) {
#pragma unroll
                for (int u = 0; u < 8; u++)
                    nxt[u] = *(const bf16x8*)(kb + (size_t)(t + 1) * 4096 + u * 512 + lane * 8);
            }
            f32x4 sacc[4];
#pragma unroll
            for (int s = 0; s < 4; s++) sacc[s] = f32x4{0.f, 0.f, 0.f, 0.f};
#pragma unroll
            for (int ks = 0; ks < 8; ks++)
#pragma unroll
                for (int s = 0; s < 4; s++)
                    sacc[s] = __builtin_amdgcn_mfma_f32_16x16x32_bf16(af[s][ks], cur[ks], sacc[s], 0, 0, 0);
            float wv = 0.f;
#pragma unroll
            for (int s = 0; s < 4; s++)
#pragma unroll
                for (int r = 0; r < 4; r++)
                    wv += fast_exp2(__builtin_fmaf(sacc[s][r], SCL, lr[s][r]));
            wv += __shfl_xor(wv, 16);
            wv += __shfl_xor(wv, 32);
            if (lg == 0) wp[t * 16 + lm] = wv;
            if (t < 31) {
#pragma unroll
                for (int u = 0; u < 8; u++) cur[u] = nxt[u];
            }
        }
    }
}

// Kernel 4: gpart[kseg,b,d] = sum over 128 keys of w_k x[b,k,d] (fp32 x).
__global__ __launch_bounds__(256) void xsum_kernel(
    const float* __restrict__ wpart, const float* __restrict__ x,
    float* __restrict__ gpart) {
    __shared__ float ldsw[128];
    int b = blockIdx.x >> 4, kseg = blockIdx.x & 15, tid = threadIdx.x;
    if (tid < 128) {
        int key = kseg * 128 + tid;
        float s = 0.f;
        for (int qt = 0; qt < 32; qt++) s += wpart[(size_t)(qt * 16 + b) * 2048 + key];
        ldsw[tid] = s;
    }
    __syncthreads();
    const float* xb = x + ((size_t)b * 2048 + kseg * 128) * 256;
    float acc = 0.f;
#pragma unroll 8
    for (int t = 0; t < 128; t++) acc += ldsw[t] * xb[(size_t)t * 256 + tid];
    gpart[(size_t)(kseg * 16 + b) * 256 + tid] = acc;
}

// Kernel 5: out[b,d] = (sum_kseg gpart)[b,:] @ Wv[:,d] + 2048*bv[d].
__global__ __launch_bounds__(256) void final_kernel(
    const float* __restrict__ gpart, const float* __restrict__ Wv,
    const float* __restrict__ bv, float* __restrict__ out) {
    __shared__ float yl[256];
    int b = blockIdx.x, tid = threadIdx.x;
    float s = 0.f;
#pragma unroll
    for (int ks = 0; ks < 16; ks++) s += gpart[(size_t)(ks * 16 + b) * 256 + tid];
    yl[tid] = s;
    __syncthreads();
    float acc = 0.f;
#pragma unroll 4
    for (int c = 0; c < 256; c++) acc += yl[c] * Wv[c * 256 + tid];
    out[b * 256 + tid] = acc + 2048.0f * bv[tid];
}

extern "C" void kernel_launch(void* const* d_in, const int* in_sizes, int n_in,
                              void* d_out, int out_size, void* d_ws, size_t ws_size,
                              hipStream_t stream) {
    const float* x  = (const float*)d_in[0];
    const float* Wq = (const float*)d_in[1];
    const float* bq = (const float*)d_in[2];
    const float* Wk = (const float*)d_in[3];
    const float* bk = (const float*)d_in[4];
    const float* Wv = (const float*)d_in[5];
    const float* bv = (const float*)d_in[6];
    float* out = (float*)d_out;

    char* ws = (char*)d_ws;
    bf16_t* wtf   = (bf16_t*)(ws);
    bf16_t* xf    = (bf16_t*)(ws + 262144);
    bf16_t* q     = (bf16_t*)(ws + 17039360);
    bf16_t* kmat  = (bf16_t*)(ws + 33816576);
    float*  wpart = (float*) (ws + 50593792);
    float*  gpart = (float*) (ws + 54788096);

    wt_kernel<<<dim3(64), dim3(256), 0, stream>>>(Wq, Wk, wtf);
    xconv_kernel<<<dim3(512), dim3(256), 0, stream>>>(x, xf);
    proj_kernel<<<dim3(512, 2), dim3(256), 0, stream>>>(xf, wtf, bq, bk, q, kmat);
    attn_fused<<<dim3(512), dim3(256), 0, stream>>>(q, kmat, wpart);
    xsum_kernel<<<dim3(256), dim3(256), 0, stream>>>(wpart, x, gpart);
    final_kernel<<<dim3(16), dim3(256), 0, stream>>>(gpart, Wv, bv, out);
}